// Round 1
// baseline (2124.806 us; speedup 1.0000x reference)
//
#include <hip/hip_runtime.h>
#include <math.h>

#define BB 32
#define TT 512
#define SS 1024
#define HH 1024

// ---------------------------------------------------------------------------
// Tiled fp32 GEMM: C[M,N] = A[M,K] @ op(B)
//   BT=true : B is [N,K] row-major (NT case: C=A*B^T)
//   BT=false: B is [K,N] row-major (NN case: C=A*B)
// 128x128 block tile, 256 threads, 8x8 micro-tile split as (4+4) halves at
// offset 0/64 to keep ds_read_b128 conflicts at 2-way (free).
// Batched via blockIdx.z with element strides sA/sB/sC.
// ---------------------------------------------------------------------------
template<bool BT>
__global__ __launch_bounds__(256) void gemm_f32(
    const float* __restrict__ A, const float* __restrict__ Bm,
    float* __restrict__ C, int M, int N, int K,
    long sA, long sB, long sC)
{
    A  += (long)blockIdx.z * sA;
    Bm += (long)blockIdx.z * sB;
    C  += (long)blockIdx.z * sC;

    __shared__ float As[8][128];
    __shared__ float Bs[8][128];

    const int tid = threadIdx.x;
    const int tx = tid & 15;         // 0..15  (N dimension)
    const int ty = tid >> 4;         // 0..15  (M dimension)
    const int bm = blockIdx.y * 128;
    const int bn = blockIdx.x * 128;

    // staging indices (A, and B in NT case): row 0..127, col4 {0,4}
    const int arow = tid >> 1;
    const int acol = (tid & 1) * 4;
    // staging indices for NN B: 8 rows x 128 cols
    const int bkrow = tid >> 5;          // 0..7
    const int bncol = (tid & 31) * 4;    // 0..124

    float acc[8][8];
#pragma unroll
    for (int i = 0; i < 8; ++i)
#pragma unroll
        for (int j = 0; j < 8; ++j) acc[i][j] = 0.0f;

    for (int k0 = 0; k0 < K; k0 += 8) {
        const float4 av = *(const float4*)(A + (long)(bm + arow) * K + k0 + acol);
        float4 bv;
        if (BT) bv = *(const float4*)(Bm + (long)(bn + arow) * K + k0 + acol);
        else    bv = *(const float4*)(Bm + (long)(k0 + bkrow) * N + bn + bncol);

        __syncthreads();   // previous inner loop done reading LDS
        As[acol + 0][arow] = av.x;
        As[acol + 1][arow] = av.y;
        As[acol + 2][arow] = av.z;
        As[acol + 3][arow] = av.w;
        if (BT) {
            Bs[acol + 0][arow] = bv.x;
            Bs[acol + 1][arow] = bv.y;
            Bs[acol + 2][arow] = bv.z;
            Bs[acol + 3][arow] = bv.w;
        } else {
            *(float4*)&Bs[bkrow][bncol] = bv;
        }
        __syncthreads();

#pragma unroll
        for (int kk = 0; kk < 8; ++kk) {
            float a[8], b[8];
            *(float4*)&a[0] = *(const float4*)&As[kk][ty * 4];
            *(float4*)&a[4] = *(const float4*)&As[kk][ty * 4 + 64];
            *(float4*)&b[0] = *(const float4*)&Bs[kk][tx * 4];
            *(float4*)&b[4] = *(const float4*)&Bs[kk][tx * 4 + 64];
#pragma unroll
            for (int i = 0; i < 8; ++i)
#pragma unroll
                for (int j = 0; j < 8; ++j)
                    acc[i][j] = fmaf(a[i], b[j], acc[i][j]);
        }
    }

#pragma unroll
    for (int i = 0; i < 8; ++i) {
        const int r = bm + ((i < 4) ? (ty * 4 + i) : (64 + ty * 4 + (i - 4)));
        float4 v0 = make_float4(acc[i][0], acc[i][1], acc[i][2], acc[i][3]);
        float4 v1 = make_float4(acc[i][4], acc[i][5], acc[i][6], acc[i][7]);
        *(float4*)(C + (long)r * N + bn + tx * 4)      = v0;
        *(float4*)(C + (long)r * N + bn + 64 + tx * 4) = v1;
    }
}

// ---------------------------------------------------------------------------
// Final GEMM with virtual concat A=[A0|A1] (K=2048), B=[N,2048] NT,
// epilogue out = tanh(acc + bias[n]).
// ---------------------------------------------------------------------------
__global__ __launch_bounds__(256) void gemm_cat_tanh(
    const float* __restrict__ A0, const float* __restrict__ A1,
    const float* __restrict__ Bm, const float* __restrict__ bias,
    float* __restrict__ C, int M, int N)
{
    const int K = 2 * HH;
    __shared__ float As[8][128];
    __shared__ float Bs[8][128];

    const int tid = threadIdx.x;
    const int tx = tid & 15;
    const int ty = tid >> 4;
    const int bm = blockIdx.y * 128;
    const int bn = blockIdx.x * 128;

    const int arow = tid >> 1;
    const int acol = (tid & 1) * 4;

    float acc[8][8];
#pragma unroll
    for (int i = 0; i < 8; ++i)
#pragma unroll
        for (int j = 0; j < 8; ++j) acc[i][j] = 0.0f;

    for (int k0 = 0; k0 < K; k0 += 8) {
        const float* Ap = (k0 < HH) ? A0 : A1;
        const int ka = (k0 < HH) ? k0 : (k0 - HH);
        const float4 av = *(const float4*)(Ap + (long)(bm + arow) * HH + ka + acol);
        const float4 bv = *(const float4*)(Bm + (long)(bn + arow) * K + k0 + acol);

        __syncthreads();
        As[acol + 0][arow] = av.x;
        As[acol + 1][arow] = av.y;
        As[acol + 2][arow] = av.z;
        As[acol + 3][arow] = av.w;
        Bs[acol + 0][arow] = bv.x;
        Bs[acol + 1][arow] = bv.y;
        Bs[acol + 2][arow] = bv.z;
        Bs[acol + 3][arow] = bv.w;
        __syncthreads();

#pragma unroll
        for (int kk = 0; kk < 8; ++kk) {
            float a[8], b[8];
            *(float4*)&a[0] = *(const float4*)&As[kk][ty * 4];
            *(float4*)&a[4] = *(const float4*)&As[kk][ty * 4 + 64];
            *(float4*)&b[0] = *(const float4*)&Bs[kk][tx * 4];
            *(float4*)&b[4] = *(const float4*)&Bs[kk][tx * 4 + 64];
#pragma unroll
            for (int i = 0; i < 8; ++i)
#pragma unroll
                for (int j = 0; j < 8; ++j)
                    acc[i][j] = fmaf(a[i], b[j], acc[i][j]);
        }
    }

#pragma unroll
    for (int i = 0; i < 8; ++i) {
        const int r = bm + ((i < 4) ? (ty * 4 + i) : (64 + ty * 4 + (i - 4)));
#pragma unroll
        for (int h = 0; h < 2; ++h) {
            const int cbase = bn + h * 64 + tx * 4;
            float4 v;
            v.x = tanhf(acc[i][h * 4 + 0] + bias[cbase + 0]);
            v.y = tanhf(acc[i][h * 4 + 1] + bias[cbase + 1]);
            v.z = tanhf(acc[i][h * 4 + 2] + bias[cbase + 2]);
            v.w = tanhf(acc[i][h * 4 + 3] + bias[cbase + 3]);
            *(float4*)(C + (long)r * N + cbase) = v;
        }
    }
}

// ---------------------------------------------------------------------------
// Mask + row softmax in place. One block per (b,t) row of S=1024.
// ---------------------------------------------------------------------------
__global__ __launch_bounds__(256) void softmax_mask(
    float* __restrict__ P, const int* __restrict__ lens)
{
    const int row = blockIdx.x;          // b*T + t
    const int b = row >> 9;              // / T (T=512)
    const int len = lens[b];
    float* p = P + (long)row * SS;

    const int tid = threadIdx.x;
    const int s0 = tid * 4;
    float4 v = *(const float4*)(p + s0);
    float vals[4] = {v.x, v.y, v.z, v.w};

    float mx = -INFINITY;
#pragma unroll
    for (int j = 0; j < 4; ++j) {
        if (s0 + j >= len) vals[j] = -INFINITY;
        mx = fmaxf(mx, vals[j]);
    }
    for (int off = 32; off; off >>= 1) mx = fmaxf(mx, __shfl_xor(mx, off, 64));

    __shared__ float redm[4];
    __shared__ float reds[4];
    const int wave = tid >> 6, lane = tid & 63;
    if (lane == 0) redm[wave] = mx;
    __syncthreads();
    mx = fmaxf(fmaxf(redm[0], redm[1]), fmaxf(redm[2], redm[3]));

    float sum = 0.0f;
#pragma unroll
    for (int j = 0; j < 4; ++j) {
        vals[j] = __expf(vals[j] - mx);   // exp(-inf)=0 for masked
        sum += vals[j];
    }
    for (int off = 32; off; off >>= 1) sum += __shfl_xor(sum, off, 64);
    if (lane == 0) reds[wave] = sum;
    __syncthreads();
    sum = reds[0] + reds[1] + reds[2] + reds[3];

    const float inv = 1.0f / sum;
    v = make_float4(vals[0] * inv, vals[1] * inv, vals[2] * inv, vals[3] * inv);
    *(float4*)(p + s0) = v;
}

// ---------------------------------------------------------------------------
extern "C" void kernel_launch(void* const* d_in, const int* in_sizes, int n_in,
                              void* d_out, int out_size, void* d_ws, size_t ws_size,
                              hipStream_t stream)
{
    const float* query = (const float*)d_in[0];   // [B,T,H]
    const float* enc   = (const float*)d_in[1];   // [B,S,H]
    const int*   lens  = (const int*)d_in[2];     // [B]
    const float* W_in  = (const float*)d_in[3];   // [H,H]
    const float* W_out = (const float*)d_in[4];   // [H,2H]
    const float* b_out = (const float*)d_in[5];   // [H]
    float* out = (float*)d_out;

    float* qw = (float*)d_ws;                       // [B*T, H]  67MB
    float* p  = qw + (size_t)BB * TT * SS;          // [B*T, S]  67MB
    float* c  = qw;                                 // reuse qw after scores

    dim3 blk(256);

    // K1: qw = query @ W_in^T   (M=B*T, N=H, K=H)
    gemm_f32<true><<<dim3(HH / 128, (BB * TT) / 128, 1), blk, 0, stream>>>(
        query, W_in, qw, BB * TT, HH, HH, 0L, 0L, 0L);

    // K2a: score[b] = qw[b] @ enc[b]^T  (M=T, N=S, K=H), batched over B
    gemm_f32<true><<<dim3(SS / 128, TT / 128, BB), blk, 0, stream>>>(
        qw, enc, p, TT, SS, HH,
        (long)TT * HH, (long)SS * HH, (long)TT * SS);

    // K2b: mask + softmax rows
    softmax_mask<<<BB * TT, 256, 0, stream>>>(p, lens);

    // K3: c[b] = p[b] @ enc[b]  (M=T, N=H, K=S), batched over B
    gemm_f32<false><<<dim3(HH / 128, TT / 128, BB), blk, 0, stream>>>(
        p, enc, c, TT, HH, SS,
        (long)TT * SS, (long)SS * HH, (long)TT * HH);

    // K4: out = tanh([query|c] @ W_out^T + b_out)  (M=B*T, N=H, K=2H)
    gemm_cat_tanh<<<dim3(HH / 128, (BB * TT) / 128, 1), blk, 0, stream>>>(
        query, c, W_out, b_out, out, BB * TT, HH);
}

// Round 2
// 1233.249 us; speedup vs baseline: 1.7229x; 1.7229x over previous
//
#include <hip/hip_runtime.h>
#include <math.h>

#define BB 32
#define TT 512
#define SS 1024
#define HH 1024

typedef __attribute__((ext_vector_type(8))) short short8;
typedef __attribute__((ext_vector_type(4))) float f32x4;
typedef __attribute__((ext_vector_type(4))) unsigned short u16x4;

__device__ __forceinline__ unsigned short f2bf(float x) {
    union { float f; unsigned int u; } a; a.f = x;
    unsigned int u = a.u;
    unsigned int r = (u + 0x7fffu + ((u >> 16) & 1u)) >> 16;
    return (unsigned short)r;
}
__device__ __forceinline__ float bf2f(unsigned short h) {
    union { unsigned int u; float f; } a; a.u = ((unsigned int)h) << 16;
    return a.f;
}

// swizzled LDS offset (element units, bf16): row stride 32 elems (64B),
// XOR k by ((r>>1)&3)<<3 -> frag ds_read_b128 is 2-way (free), writes ~4-way.
__device__ __forceinline__ int lds_off(int r, int k) {
    return r * 32 + (k ^ (((r >> 1) & 3) << 3));
}

// ---------------------------------------------------------------------------
// Split-bf16 MFMA GEMM, NT: C[M,N] = A[M,K] @ B[N,K]^T  (+ optional concat A,
// optional tanh(x+bias) epilogue). 128x128 tile, 4 waves (2x2), BK=32,
// 16x16x32 bf16 MFMA, 3-product Ootomo split (hi*hi + hi*lo + lo*hi).
// A rows are always HH-wide (CAT: two HH-wide halves). B is [N][K] row-major.
// ---------------------------------------------------------------------------
template<bool CAT, bool TANH>
__global__ __launch_bounds__(256) void gemm_split(
    const float* __restrict__ A0, const float* __restrict__ A1,
    const float* __restrict__ Bp, const float* __restrict__ bias,
    float* __restrict__ C, int K, int N,
    long sA, long sB, long sC)
{
    A0 += (long)blockIdx.z * sA;
    Bp += (long)blockIdx.z * sB;
    C  += (long)blockIdx.z * sC;

    __shared__ unsigned short Ah[128 * 32], Al[128 * 32];
    __shared__ unsigned short Bh[128 * 32], Bl[128 * 32];

    const int tid = threadIdx.x;
    const int bm = blockIdx.y * 128;
    const int bn = blockIdx.x * 128;

    const int l  = tid & 63;
    const int w  = tid >> 6;
    const int wm = (w >> 1) * 64;       // wave row offset
    const int wn = (w & 1) * 64;        // wave col offset
    const int fr = l & 15;              // fragment row (m or n within 16)
    const int kb = (l >> 4) * 8;        // fragment k-offset (8 contiguous)

    f32x4 acc[4][4] = {};

    float4 ra[4], rb[4], ra2[4], rb2[4];

#define LOAD_STEP(RA, RB, K0)                                                  \
    {                                                                          \
        const float* Ap_ = A0; int ka_ = (K0);                                 \
        if (CAT && (K0) >= HH) { Ap_ = A1; ka_ = (K0) - HH; }                  \
        _Pragma("unroll")                                                      \
        for (int i_ = 0; i_ < 4; ++i_) {                                       \
            int idx_ = tid + 256 * i_;                                         \
            int r_ = idx_ >> 3, kq_ = (idx_ & 7) * 4;                          \
            RA[i_] = *(const float4*)(Ap_ + (long)(bm + r_) * HH + ka_ + kq_); \
            RB[i_] = *(const float4*)(Bp  + (long)(bn + r_) * K  + (K0) + kq_);\
        }                                                                      \
    }

#define WRITE_STEP(RA, RB)                                                     \
    {                                                                          \
        _Pragma("unroll")                                                      \
        for (int i_ = 0; i_ < 4; ++i_) {                                       \
            int idx_ = tid + 256 * i_;                                         \
            int r_ = idx_ >> 3, kq_ = (idx_ & 7) * 4;                          \
            int off_ = lds_off(r_, kq_);                                       \
            float va_[4] = {RA[i_].x, RA[i_].y, RA[i_].z, RA[i_].w};           \
            float vb_[4] = {RB[i_].x, RB[i_].y, RB[i_].z, RB[i_].w};           \
            u16x4 ah_, al_, bh_, bl_;                                          \
            _Pragma("unroll")                                                  \
            for (int j_ = 0; j_ < 4; ++j_) {                                   \
                unsigned short h_ = f2bf(va_[j_]);                             \
                ah_[j_] = h_; al_[j_] = f2bf(va_[j_] - bf2f(h_));              \
                unsigned short g_ = f2bf(vb_[j_]);                             \
                bh_[j_] = g_; bl_[j_] = f2bf(vb_[j_] - bf2f(g_));              \
            }                                                                  \
            *(u16x4*)&Ah[off_] = ah_;                                          \
            *(u16x4*)&Al[off_] = al_;                                          \
            *(u16x4*)&Bh[off_] = bh_;                                          \
            *(u16x4*)&Bl[off_] = bl_;                                          \
        }                                                                      \
    }

#define COMPUTE_STEP()                                                         \
    {                                                                          \
        short8 fah[4], fal[4], fbh[4], fbl[4];                                 \
        _Pragma("unroll")                                                      \
        for (int i_ = 0; i_ < 4; ++i_) {                                       \
            int oa_ = lds_off(wm + i_ * 16 + fr, kb);                          \
            fah[i_] = *(const short8*)&Ah[oa_];                                \
            fal[i_] = *(const short8*)&Al[oa_];                                \
            int ob_ = lds_off(wn + i_ * 16 + fr, kb);                          \
            fbh[i_] = *(const short8*)&Bh[ob_];                                \
            fbl[i_] = *(const short8*)&Bl[ob_];                                \
        }                                                                      \
        _Pragma("unroll")                                                      \
        for (int i_ = 0; i_ < 4; ++i_)                                         \
            _Pragma("unroll")                                                  \
            for (int j_ = 0; j_ < 4; ++j_) {                                   \
                acc[i_][j_] = __builtin_amdgcn_mfma_f32_16x16x32_bf16(         \
                    fal[i_], fbh[j_], acc[i_][j_], 0, 0, 0);                   \
                acc[i_][j_] = __builtin_amdgcn_mfma_f32_16x16x32_bf16(         \
                    fah[i_], fbl[j_], acc[i_][j_], 0, 0, 0);                   \
                acc[i_][j_] = __builtin_amdgcn_mfma_f32_16x16x32_bf16(         \
                    fah[i_], fbh[j_], acc[i_][j_], 0, 0, 0);                   \
            }                                                                  \
    }

    LOAD_STEP(ra, rb, 0)
    int k0 = 0;
    while (true) {
        __syncthreads();               // previous compute done reading LDS
        WRITE_STEP(ra, rb)
        bool more = (k0 + 32 < K);
        if (more) LOAD_STEP(ra2, rb2, k0 + 32)
        __syncthreads();               // LDS tile visible
        COMPUTE_STEP()
        k0 += 32;
        if (!more) break;

        __syncthreads();
        WRITE_STEP(ra2, rb2)
        more = (k0 + 32 < K);
        if (more) LOAD_STEP(ra, rb, k0 + 32)
        __syncthreads();
        COMPUTE_STEP()
        k0 += 32;
        if (!more) break;
    }

#undef LOAD_STEP
#undef WRITE_STEP
#undef COMPUTE_STEP

    // Epilogue: D[row=(l>>4)*4+r][col=l&15] per frag.
#pragma unroll
    for (int i = 0; i < 4; ++i) {
        const int row0 = bm + wm + i * 16 + (l >> 4) * 4;
#pragma unroll
        for (int j = 0; j < 4; ++j) {
            const int col = bn + wn + j * 16 + fr;
            float bv = TANH ? bias[col] : 0.0f;
#pragma unroll
            for (int r = 0; r < 4; ++r) {
                float v = acc[i][j][r];
                if (TANH) {
                    float e = __expf(2.0f * (v + bv));
                    v = 1.0f - 2.0f / (e + 1.0f);   // tanh
                }
                C[(long)(row0 + r) * N + col] = v;
            }
        }
    }
}

// ---------------------------------------------------------------------------
// fp32 vector GEMM, NN (for K3: c = P @ enc). Unchanged from round 0.
// ---------------------------------------------------------------------------
__global__ __launch_bounds__(256) void gemm_f32_nn(
    const float* __restrict__ A, const float* __restrict__ Bm,
    float* __restrict__ C, int M, int N, int K,
    long sA, long sB, long sC)
{
    A  += (long)blockIdx.z * sA;
    Bm += (long)blockIdx.z * sB;
    C  += (long)blockIdx.z * sC;

    __shared__ float As[8][128];
    __shared__ float Bs[8][128];

    const int tid = threadIdx.x;
    const int tx = tid & 15;
    const int ty = tid >> 4;
    const int bm = blockIdx.y * 128;
    const int bn = blockIdx.x * 128;

    const int arow = tid >> 1;
    const int acol = (tid & 1) * 4;
    const int bkrow = tid >> 5;
    const int bncol = (tid & 31) * 4;

    float acc[8][8];
#pragma unroll
    for (int i = 0; i < 8; ++i)
#pragma unroll
        for (int j = 0; j < 8; ++j) acc[i][j] = 0.0f;

    for (int k0 = 0; k0 < K; k0 += 8) {
        const float4 av = *(const float4*)(A + (long)(bm + arow) * K + k0 + acol);
        const float4 bv = *(const float4*)(Bm + (long)(k0 + bkrow) * N + bn + bncol);

        __syncthreads();
        As[acol + 0][arow] = av.x;
        As[acol + 1][arow] = av.y;
        As[acol + 2][arow] = av.z;
        As[acol + 3][arow] = av.w;
        *(float4*)&Bs[bkrow][bncol] = bv;
        __syncthreads();

#pragma unroll
        for (int kk = 0; kk < 8; ++kk) {
            float a[8], b[8];
            *(float4*)&a[0] = *(const float4*)&As[kk][ty * 4];
            *(float4*)&a[4] = *(const float4*)&As[kk][ty * 4 + 64];
            *(float4*)&b[0] = *(const float4*)&Bs[kk][tx * 4];
            *(float4*)&b[4] = *(const float4*)&Bs[kk][tx * 4 + 64];
#pragma unroll
            for (int i = 0; i < 8; ++i)
#pragma unroll
                for (int j = 0; j < 8; ++j)
                    acc[i][j] = fmaf(a[i], b[j], acc[i][j]);
        }
    }

#pragma unroll
    for (int i = 0; i < 8; ++i) {
        const int r = bm + ((i < 4) ? (ty * 4 + i) : (64 + ty * 4 + (i - 4)));
        float4 v0 = make_float4(acc[i][0], acc[i][1], acc[i][2], acc[i][3]);
        float4 v1 = make_float4(acc[i][4], acc[i][5], acc[i][6], acc[i][7]);
        *(float4*)(C + (long)r * N + bn + tx * 4)      = v0;
        *(float4*)(C + (long)r * N + bn + 64 + tx * 4) = v1;
    }
}

// ---------------------------------------------------------------------------
// Mask + row softmax in place. One block per (b,t) row of S=1024.
// ---------------------------------------------------------------------------
__global__ __launch_bounds__(256) void softmax_mask(
    float* __restrict__ P, const int* __restrict__ lens)
{
    const int row = blockIdx.x;
    const int b = row >> 9;             // / T (T=512)
    const int len = lens[b];
    float* p = P + (long)row * SS;

    const int tid = threadIdx.x;
    const int s0 = tid * 4;
    float4 v = *(const float4*)(p + s0);
    float vals[4] = {v.x, v.y, v.z, v.w};

    float mx = -INFINITY;
#pragma unroll
    for (int j = 0; j < 4; ++j) {
        if (s0 + j >= len) vals[j] = -INFINITY;
        mx = fmaxf(mx, vals[j]);
    }
    for (int off = 32; off; off >>= 1) mx = fmaxf(mx, __shfl_xor(mx, off, 64));

    __shared__ float redm[4];
    __shared__ float reds[4];
    const int wave = tid >> 6, lane = tid & 63;
    if (lane == 0) redm[wave] = mx;
    __syncthreads();
    mx = fmaxf(fmaxf(redm[0], redm[1]), fmaxf(redm[2], redm[3]));

    float sum = 0.0f;
#pragma unroll
    for (int j = 0; j < 4; ++j) {
        vals[j] = __expf(vals[j] - mx);
        sum += vals[j];
    }
    for (int off = 32; off; off >>= 1) sum += __shfl_xor(sum, off, 64);
    if (lane == 0) reds[wave] = sum;
    __syncthreads();
    sum = reds[0] + reds[1] + reds[2] + reds[3];

    const float inv = 1.0f / sum;
    v = make_float4(vals[0] * inv, vals[1] * inv, vals[2] * inv, vals[3] * inv);
    *(float4*)(p + s0) = v;
}

// ---------------------------------------------------------------------------
extern "C" void kernel_launch(void* const* d_in, const int* in_sizes, int n_in,
                              void* d_out, int out_size, void* d_ws, size_t ws_size,
                              hipStream_t stream)
{
    const float* query = (const float*)d_in[0];   // [B,T,H]
    const float* enc   = (const float*)d_in[1];   // [B,S,H]
    const int*   lens  = (const int*)d_in[2];     // [B]
    const float* W_in  = (const float*)d_in[3];   // [H,H]
    const float* W_out = (const float*)d_in[4];   // [H,2H]
    const float* b_out = (const float*)d_in[5];   // [H]
    float* out = (float*)d_out;

    float* qw = (float*)d_ws;                     // [B*T, H]
    float* p  = qw + (size_t)BB * TT * SS;        // [B*T, S]
    float* c  = qw;                               // reuse qw after scores

    // K1: qw = query @ W_in^T   (M=B*T=16384, N=H, K=H) — split-bf16 MFMA
    gemm_split<false, false><<<dim3(HH / 128, (BB * TT) / 128, 1), 256, 0, stream>>>(
        query, nullptr, W_in, nullptr, qw, HH, HH, 0L, 0L, 0L);

    // K2: score[b] = qw[b] @ enc[b]^T  (M=T, N=S, K=H), batched — split MFMA
    gemm_split<false, false><<<dim3(SS / 128, TT / 128, BB), 256, 0, stream>>>(
        qw, nullptr, enc, nullptr, p, HH, SS,
        (long)TT * HH, (long)SS * HH, (long)TT * SS);

    // K2b: mask + softmax rows
    softmax_mask<<<BB * TT, 256, 0, stream>>>(p, lens);

    // K3: c[b] = p[b] @ enc[b]  (M=T, N=H, K=S), batched — fp32 vector (NN)
    gemm_f32_nn<<<dim3(HH / 128, TT / 128, BB), 256, 0, stream>>>(
        p, enc, c, TT, HH, SS,
        (long)TT * SS, (long)SS * HH, (long)TT * HH);

    // K4: out = tanh([query|c] @ W_out^T + b_out)  (M=B*T, N=H, K=2H) — split MFMA
    gemm_split<true, true><<<dim3(HH / 128, (BB * TT) / 128, 1), 256, 0, stream>>>(
        query, c, W_out, b_out, out, 2 * HH, HH, 0L, 0L, 0L);
}

// Round 3
// 686.843 us; speedup vs baseline: 3.0936x; 1.7955x over previous
//
#include <hip/hip_runtime.h>
#include <hip/hip_bf16.h>
#include <math.h>

#define BB 32
#define TT 512
#define SS 1024
#define HH 1024

typedef __attribute__((ext_vector_type(8))) short short8;
typedef __attribute__((ext_vector_type(4))) float f32x4;
typedef __attribute__((ext_vector_type(4))) unsigned short u16x4;
typedef unsigned short u16;

__device__ __forceinline__ u16 f2h(float x) {
    return __builtin_bit_cast(u16, __float2bfloat16(x));
}
__device__ __forceinline__ float h2f(u16 h) {
    union { unsigned int u; float f; } a; a.u = ((unsigned int)h) << 16;
    return a.f;
}

// chunk swizzle: row r, 16B chunks (8 bf16). S(r) chosen so that frag reads
// (consecutive r, fixed chunk) spread 2-way (free) AND transposed writes
// (r stride 4) still cycle all 4 slots.
__device__ __forceinline__ int swz(int r) { return (r ^ (r >> 2)) & 3; }
// element offset of (row r, k kk) in a [128][32] u16 LDS tile
__device__ __forceinline__ int lds_off(int r, int kk) {
    return r * 32 + (kk ^ (swz(r) << 3));
}

// async global->LDS, 16B per lane. LDS dest = wave-uniform base + lane*16.
__device__ __forceinline__ void gll16(const void* g, void* l) {
    __builtin_amdgcn_global_load_lds(
        (const __attribute__((address_space(1))) void*)g,
        (__attribute__((address_space(3))) void*)l, 16, 0, 0);
}

enum { B_SPLIT = 0, B_F32 = 1, B_F32T = 2 };
enum { E_F32 = 0, E_SPLIT = 1, E_TANH = 2 };

// ---------------------------------------------------------------------------
// Pre-split bf16 MFMA GEMM (NT): C = A @ B^T.
// NPROD=3: Al*Bh + Ah*Bl + Ah*Bh (full Ootomo split). NPROD=2: Ah*(Bh+Bl).
// BMODE: B_SPLIT = B pre-split, staged via global_load_lds (pre-swizzled src)
//        B_F32   = B fp32 [n][k] rows, converted in-kernel (linear writes)
//        B_F32T  = B fp32 [k][n] rows, converted + transposed in-kernel
// 128x128 tile, 4 waves (2x2), BK=32, 16x16x32 bf16 MFMA.
// ---------------------------------------------------------------------------
template<int NPROD, int BMODE, int EPI, bool CAT>
__global__ __launch_bounds__(256) void gemm_ps(
    const u16* __restrict__ Ah_g, const u16* __restrict__ Al_g,
    const u16* __restrict__ A2h_g, const u16* __restrict__ A2l_g,
    const u16* __restrict__ Bh_g, const u16* __restrict__ Bl_g,
    const float* __restrict__ Bf_g,
    const float* __restrict__ bias,
    float* __restrict__ Cf, u16* __restrict__ Ch, u16* __restrict__ Cl,
    int K, int N,
    long sA, long sB, long sC)
{
    const long z = blockIdx.z;
    Ah_g += z * sA;
    if (NPROD == 3) Al_g += z * sA;
    if (BMODE == B_SPLIT) { Bh_g += z * sB; Bl_g += z * sB; }
    else                  { Bf_g += z * sB; }
    if (EPI == E_SPLIT)   { Ch += z * sC; Cl += z * sC; }
    else                  { Cf += z * sC; }

    __shared__ u16 Ahs[128 * 32];
    __shared__ u16 Als[(NPROD == 3) ? 128 * 32 : 8];
    __shared__ u16 Bhs[128 * 32];
    __shared__ u16 Bls[128 * 32];

    const int tid = threadIdx.x;
    const int l = tid & 63, w = tid >> 6;
    const int bm = blockIdx.y * 128, bn = blockIdx.x * 128;
    const int wm = (w >> 1) * 64, wn = (w & 1) * 64;
    const int fr = l & 15, kb = (l >> 4) * 8;

    f32x4 acc[4][4] = {};

    // ---- staging helpers ----
    const int sr = w * 32 + (l >> 2);   // staging row for gll (h adds 16)
    const int sc = l & 3;               // staging chunk

    auto stageA = [&](int k0) {
        const u16* ah = Ah_g; const u16* al = Al_g; int ka = k0;
        if (CAT && k0 >= HH) { ah = A2h_g; al = A2l_g; ka = k0 - HH; }
        const int ldA = CAT ? HH : K;
#pragma unroll
        for (int h = 0; h < 2; ++h) {
            const int r = sr + h * 16;
            const long off = (long)(bm + r) * ldA + ka + ((sc ^ swz(r)) << 3);
            gll16(ah + off, &Ahs[(w * 2 + h) * 512]);
            if (NPROD == 3) gll16(al + off, &Als[(w * 2 + h) * 512]);
        }
    };
    auto stageB = [&](int k0) {   // B_SPLIT only
#pragma unroll
        for (int h = 0; h < 2; ++h) {
            const int r = sr + h * 16;
            const long off = (long)(bn + r) * K + k0 + ((sc ^ swz(r)) << 3);
            gll16(Bh_g + off, &Bhs[(w * 2 + h) * 512]);
            gll16(Bl_g + off, &Bls[(w * 2 + h) * 512]);
        }
    };
    auto bload = [&](f32x4* rb, int k0) {   // B_F32: [n][k] rows, ld=K
#pragma unroll
        for (int q = 0; q < 4; ++q) {
            int idx = tid + 256 * q;
            int r = idx >> 3, kq = (idx & 7) * 4;
            rb[q] = *(const f32x4*)(Bf_g + (long)(bn + r) * K + k0 + kq);
        }
    };
    auto bwrite = [&](const f32x4* rb) {
#pragma unroll
        for (int q = 0; q < 4; ++q) {
            int idx = tid + 256 * q;
            int r = idx >> 3, kq = (idx & 7) * 4;
            u16x4 hi, lo;
#pragma unroll
            for (int e = 0; e < 4; ++e) {
                u16 h_ = f2h(rb[q][e]);
                hi[e] = h_; lo[e] = f2h(rb[q][e] - h2f(h_));
            }
            int off = lds_off(r, kq);
            *(u16x4*)&Bhs[off] = hi;
            *(u16x4*)&Bls[off] = lo;
        }
    };
    auto bloadT = [&](f32x4* rb, int k0) {  // B_F32T: [k][n] rows, ld=N
#pragma unroll
        for (int q = 0; q < 4; ++q) {
            int row = 8 * w + 4 * (l >> 5) + q;      // local k
            int n4 = (l & 31) * 4;
            rb[q] = *(const f32x4*)(Bf_g + (long)(k0 + row) * N + bn + n4);
        }
    };
    auto bwriteT = [&](const f32x4* rb) {
        const int kb4 = 8 * w + 4 * (l >> 5);
#pragma unroll
        for (int e = 0; e < 4; ++e) {
            int n = (l & 31) * 4 + e;
            u16x4 hi, lo;
#pragma unroll
            for (int q = 0; q < 4; ++q) {
                float x = rb[q][e];
                u16 h_ = f2h(x);
                hi[q] = h_; lo[q] = f2h(x - h2f(h_));
            }
            int off = lds_off(n, kb4);
            *(u16x4*)&Bhs[off] = hi;
            *(u16x4*)&Bls[off] = lo;
        }
    };

    auto compute = [&]() {
        short8 fbh[4], fbl[4];
#pragma unroll
        for (int j = 0; j < 4; ++j) {
            int ob = lds_off(wn + j * 16 + fr, kb);
            fbh[j] = *(const short8*)&Bhs[ob];
            fbl[j] = *(const short8*)&Bls[ob];
        }
#pragma unroll
        for (int i = 0; i < 4; ++i) {
            int oa = lds_off(wm + i * 16 + fr, kb);
            short8 fah = *(const short8*)&Ahs[oa];
            short8 fal = fah;
            if (NPROD == 3) fal = *(const short8*)&Als[oa];
#pragma unroll
            for (int j = 0; j < 4; ++j) {
                if (NPROD == 3) {
                    acc[i][j] = __builtin_amdgcn_mfma_f32_16x16x32_bf16(fal, fbh[j], acc[i][j], 0, 0, 0);
                    acc[i][j] = __builtin_amdgcn_mfma_f32_16x16x32_bf16(fah, fbl[j], acc[i][j], 0, 0, 0);
                    acc[i][j] = __builtin_amdgcn_mfma_f32_16x16x32_bf16(fah, fbh[j], acc[i][j], 0, 0, 0);
                } else {
                    acc[i][j] = __builtin_amdgcn_mfma_f32_16x16x32_bf16(fah, fbh[j], acc[i][j], 0, 0, 0);
                    acc[i][j] = __builtin_amdgcn_mfma_f32_16x16x32_bf16(fah, fbl[j], acc[i][j], 0, 0, 0);
                }
            }
        }
    };

    // ---- K loop ----
    if (BMODE == B_SPLIT) {
        for (int k0 = 0; k0 < K; k0 += 32) {
            __syncthreads();                 // prev compute done reading LDS
            stageA(k0);
            stageB(k0);
            __syncthreads();                 // vmcnt(0) drain -> tile visible
            compute();
        }
    } else {
        f32x4 r0[4], r1[4];
        if (BMODE == B_F32) bload(r0, 0); else bloadT(r0, 0);
        for (int k0 = 0; k0 < K; k0 += 64) {
            __syncthreads();
            if (BMODE == B_F32) bwrite(r0); else bwriteT(r0);
            stageA(k0);
            __syncthreads();
            if (BMODE == B_F32) bload(r1, k0 + 32); else bloadT(r1, k0 + 32);
            compute();

            __syncthreads();
            if (BMODE == B_F32) bwrite(r1); else bwriteT(r1);
            stageA(k0 + 32);
            __syncthreads();
            if (k0 + 64 < K) { if (BMODE == B_F32) bload(r0, k0 + 64); else bloadT(r0, k0 + 64); }
            compute();
        }
    }

    // ---- epilogue: D[row=(l>>4)*4+r][col=l&15] per frag ----
#pragma unroll
    for (int i = 0; i < 4; ++i) {
        const int row0 = bm + wm + i * 16 + (l >> 4) * 4;
#pragma unroll
        for (int j = 0; j < 4; ++j) {
            const int col = bn + wn + j * 16 + fr;
            float bv = (EPI == E_TANH) ? bias[col] : 0.0f;
#pragma unroll
            for (int r = 0; r < 4; ++r) {
                float v = acc[i][j][r];
                long o = (long)(row0 + r) * N + col;
                if (EPI == E_TANH) {
                    float e = __expf(2.0f * (v + bv));
                    Cf[o] = 1.0f - 2.0f / (e + 1.0f);
                } else if (EPI == E_SPLIT) {
                    u16 h_ = f2h(v);
                    Ch[o] = h_;
                    Cl[o] = f2h(v - h2f(h_));
                } else {
                    Cf[o] = v;
                }
            }
        }
    }
}

// ---------------------------------------------------------------------------
// fp32 -> (hi, lo) bf16 splitter, grid-stride, vectorized.
// ---------------------------------------------------------------------------
__global__ __launch_bounds__(256) void split_f32(
    const float* __restrict__ in, u16* __restrict__ hi, u16* __restrict__ lo,
    long n4)
{
    long i = (long)blockIdx.x * blockDim.x + threadIdx.x;
    const long stride = (long)gridDim.x * blockDim.x;
    for (; i < n4; i += stride) {
        f32x4 v = *(const f32x4*)(in + i * 4);
        u16x4 h4, l4;
#pragma unroll
        for (int e = 0; e < 4; ++e) {
            u16 h_ = f2h(v[e]);
            h4[e] = h_; l4[e] = f2h(v[e] - h2f(h_));
        }
        *(u16x4*)(hi + i * 4) = h4;
        *(u16x4*)(lo + i * 4) = l4;
    }
}

// ---------------------------------------------------------------------------
// Mask + row softmax: scores fp32 in, P bf16(hi) out. One block per (b,t).
// ---------------------------------------------------------------------------
__global__ __launch_bounds__(256) void softmax_mask(
    const float* __restrict__ Sc, u16* __restrict__ Ph,
    const int* __restrict__ lens)
{
    const int row = blockIdx.x;
    const int b = row >> 9;             // / T (T=512)
    const int len = lens[b];
    const float* p = Sc + (long)row * SS;

    const int tid = threadIdx.x;
    const int s0 = tid * 4;
    f32x4 v = *(const f32x4*)(p + s0);
    float vals[4] = {v.x, v.y, v.z, v.w};

    float mx = -INFINITY;
#pragma unroll
    for (int j = 0; j < 4; ++j) {
        if (s0 + j >= len) vals[j] = -INFINITY;
        mx = fmaxf(mx, vals[j]);
    }
    for (int off = 32; off; off >>= 1) mx = fmaxf(mx, __shfl_xor(mx, off, 64));

    __shared__ float redm[4];
    __shared__ float reds[4];
    const int wave = tid >> 6, lane = tid & 63;
    if (lane == 0) redm[wave] = mx;
    __syncthreads();
    mx = fmaxf(fmaxf(redm[0], redm[1]), fmaxf(redm[2], redm[3]));

    float sum = 0.0f;
#pragma unroll
    for (int j = 0; j < 4; ++j) {
        vals[j] = __expf(vals[j] - mx);
        sum += vals[j];
    }
    for (int off = 32; off; off >>= 1) sum += __shfl_xor(sum, off, 64);
    if (lane == 0) reds[wave] = sum;
    __syncthreads();
    sum = reds[0] + reds[1] + reds[2] + reds[3];

    const float inv = 1.0f / sum;
    u16x4 o;
#pragma unroll
    for (int j = 0; j < 4; ++j) o[j] = f2h(vals[j] * inv);
    *(u16x4*)(Ph + (long)row * SS + s0) = o;
}

// ---------------------------------------------------------------------------
extern "C" void kernel_launch(void* const* d_in, const int* in_sizes, int n_in,
                              void* d_out, int out_size, void* d_ws, size_t ws_size,
                              hipStream_t stream)
{
    const float* query = (const float*)d_in[0];   // [B,T,H]
    const float* enc   = (const float*)d_in[1];   // [B,S,H]
    const int*   lens  = (const int*)d_in[2];     // [B]
    const float* W_in  = (const float*)d_in[3];   // [H,H]
    const float* W_out = (const float*)d_in[4];   // [H,2H]
    const float* b_out = (const float*)d_in[5];   // [H]
    float* out = (float*)d_out;

    const long MQ = (long)BB * TT;                // 16384

    u16* qh  = (u16*)d_ws;                        // [M,H] 32MiB
    u16* ql  = qh  + MQ * HH;                     // 32MiB
    u16* wih = ql  + MQ * HH;                     // [H,H] 2MiB
    u16* wil = wih + (long)HH * HH;
    u16* woh = wil + (long)HH * HH;               // [H,2H] 4MiB
    u16* wol = woh + (long)HH * 2 * HH;
    u16* qwh = wol + (long)HH * 2 * HH;           // [M,H] 32MiB
    u16* qwl = qwh + MQ * HH;                     // 32MiB
    u16* ph  = qwl + MQ * HH;                     // [M,S] 32MiB
    float* scores = (float*)(ph + MQ * SS);       // [M,S] 64MiB
    u16* ch = qwh;                                // reuse (qw dead after K2)
    u16* cl = qwl;

    // Pre-split fp32 operands -> bf16 hi/lo
    split_f32<<<2048, 256, 0, stream>>>(query, qh, ql, MQ * HH / 4);
    split_f32<<<512, 256, 0, stream>>>(W_in, wih, wil, (long)HH * HH / 4);
    split_f32<<<512, 256, 0, stream>>>(W_out, woh, wol, (long)HH * 2 * HH / 4);

    // K1: qw = query @ W_in^T   (M=16384, N=1024, K=1024), out split
    gemm_ps<3, B_SPLIT, E_SPLIT, false><<<dim3(8, 128, 1), 256, 0, stream>>>(
        qh, ql, nullptr, nullptr, wih, wil, nullptr, nullptr,
        nullptr, qwh, qwl, HH, HH, 0L, 0L, 0L);

    // K2: score[b] = qw[b] @ enc[b]^T  (M=512, N=1024, K=1024) x32
    gemm_ps<3, B_F32, E_F32, false><<<dim3(8, 4, 32), 256, 0, stream>>>(
        qwh, qwl, nullptr, nullptr, nullptr, nullptr, enc, nullptr,
        scores, nullptr, nullptr, HH, SS,
        (long)TT * HH, (long)SS * HH, (long)TT * SS);

    // softmax + mask -> P (bf16 hi)
    softmax_mask<<<BB * TT, 256, 0, stream>>>(scores, ph, lens);

    // K3: c[b] = P[b] @ enc[b]  (M=512, N=1024, K=1024) x32, B transposed
    gemm_ps<2, B_F32T, E_SPLIT, false><<<dim3(8, 4, 32), 256, 0, stream>>>(
        ph, nullptr, nullptr, nullptr, nullptr, nullptr, enc, nullptr,
        nullptr, ch, cl, SS, HH,
        (long)TT * SS, (long)SS * HH, (long)TT * HH);

    // K4: out = tanh([query|c] @ W_out^T + b_out)  (M=16384, N=1024, K=2048)
    gemm_ps<3, B_SPLIT, E_TANH, true><<<dim3(8, 128, 1), 256, 0, stream>>>(
        qh, ql, ch, cl, woh, wol, nullptr, b_out,
        out, nullptr, nullptr, 2 * HH, HH, 0L, 0L, 0L);
}

// Round 4
// 503.636 us; speedup vs baseline: 4.2189x; 1.3638x over previous
//
#include <hip/hip_runtime.h>
#include <math.h>

#define BB 32
#define TT 512
#define SS 1024
#define HH 1024

typedef __attribute__((ext_vector_type(8))) short short8;
typedef __attribute__((ext_vector_type(4))) float f32x4;
typedef __attribute__((ext_vector_type(4))) unsigned short u16x4;
typedef unsigned short u16;

__device__ __forceinline__ u16 f2h(float x) {
    union { float f; unsigned int u; } a; a.f = x;
    unsigned int u = a.u;
    return (u16)((u + 0x7fffu + ((u >> 16) & 1u)) >> 16);
}
__device__ __forceinline__ float h2f(u16 h) {
    union { unsigned int u; float f; } a; a.u = ((unsigned int)h) << 16;
    return a.f;
}

// async global->LDS, 16B per lane; LDS dest = wave-uniform base + lane*16.
__device__ __forceinline__ void gll16(const u16* g, u16* l) {
    __builtin_amdgcn_global_load_lds(
        (const __attribute__((address_space(1))) void*)g,
        (__attribute__((address_space(3))) void*)l, 16, 0, 0);
}

enum { E_F32 = 0, E_SPLIT = 1, E_TANH = 2, E_H = 3 };

struct Segs { const u16* a[4]; const u16* b[4]; };

// ---------------------------------------------------------------------------
// 256x256 8-phase bf16 NT GEMM: C = A' @ B'^T over K' = NSEG*1024, where
// segment s uses base pointers sg.a[s] / sg.b[s] (K'-extension of the
// Ootomo split: 3-product == plain GEMM over [Ah|Ah|Al]x[Bh|Bl|Bh]).
// 512 thr = 8 waves (2M x 4N), BK=64 (2 k-halves), LDS 128KiB double-buffered.
// Counted vmcnt(4) at phases 2 & 4 (never 0 mid-loop); setprio around MFMA.
// ---------------------------------------------------------------------------
template<int NSEG, int EPI>
__global__ __launch_bounds__(512, 2) void gemm8(
    Segs sg, int ldA, int ldB, int zshift,
    long sA, long sB, long sC,
    const float* __restrict__ bias,
    float* __restrict__ Cf, u16* __restrict__ Ch, u16* __restrict__ Cl,
    int ldC)
{
    __shared__ u16 lds[2][2][2][256 * 32];   // [buf][A/B][khalf][row*32+k]

    const int tid = threadIdx.x;
    const int l = tid & 63, w = tid >> 6;
    const int wr = w >> 2, wc = w & 3;       // wave grid 2(M) x 4(N)
    const int fr = l & 15, g = l >> 4;

    // block decode: XCD-chunked so A-panel-sharing blocks land on one XCD
    const int id = blockIdx.x;
    const int v = ((id & 7) << 5) | (id >> 3);
    const int z = v >> zshift;
    const int rest = v & ((1 << zshift) - 1);
    const int bm = (rest >> 2) * 256;
    const int bn = (rest & 3) * 256;

    const u16* Aseg[4]; const u16* Bseg[4];
#pragma unroll
    for (int s = 0; s < NSEG; ++s) {
        Aseg[s] = sg.a[s] + (long)z * sA;
        Bseg[s] = sg.b[s] + (long)z * sB;
    }
    if (EPI == E_F32 || EPI == E_TANH) Cf += (long)z * sC;
    else { Ch += (long)z * sC; if (EPI == E_SPLIT) Cl += (long)z * sC; }

    f32x4 acc[8][4] = {};

    auto stage = [&](int tile, int khalf, int tensor) {
        const int k0g = tile * 64 + khalf * 32;
        const int seg = k0g >> 10, kl = k0g & 1023;
        const u16* base = tensor ? Bseg[seg] : Aseg[seg];
        const int ld = tensor ? ldB : ldA;
        const int rb = tensor ? bn : bm;
        u16* lbase = &lds[tile & 1][tensor][khalf][0];
#pragma unroll
        for (int r = 0; r < 2; ++r) {
            const int p = r * 512 + tid;           // chunk index 0..1023
            const int row = p >> 2, ch = p & 3;
            const int kc = ch ^ ((row >> 1) & 3);  // pre-swizzled global src
            gll16(base + (long)(rb + row) * ld + kl + kc * 8,
                  lbase + ((r * 512 + (tid & ~63)) << 3));
        }
    };

    auto ldfrag = [&](int cur, int tensor, int ks, int row) -> short8 {
        const int off = (row * 4 + (g ^ ((row >> 1) & 3))) * 8;
        return *(const short8*)&lds[cur][tensor][ks][off];
    };

    // prologue: stage tile 0 fully, drain, barrier
    stage(0, 0, 0); stage(0, 0, 1); stage(0, 1, 0); stage(0, 1, 1);
    asm volatile("s_waitcnt vmcnt(0)" ::: "memory");
    __builtin_amdgcn_s_barrier();

    const int NT = NSEG * 16;

#define PHASE(KS, MH, ST_KH, ST_TEN, WAITCODE)                                 \
    {                                                                          \
        if (MH == 0) {                                                         \
            _Pragma("unroll") for (int j = 0; j < 4; ++j)                      \
                fb[j] = ldfrag(cur, 1, KS, wc * 64 + j * 16 + fr);             \
        }                                                                      \
        _Pragma("unroll") for (int i = 0; i < 4; ++i)                          \
            fa[i] = ldfrag(cur, 0, KS, wr * 128 + (MH * 4 + i) * 16 + fr);     \
        if (notLast) stage(t + 1, ST_KH, ST_TEN);                              \
        WAITCODE                                                               \
        __builtin_amdgcn_s_barrier();                                          \
        __builtin_amdgcn_s_setprio(1);                                         \
        _Pragma("unroll") for (int i = 0; i < 4; ++i)                          \
            _Pragma("unroll") for (int j = 0; j < 4; ++j)                      \
                acc[MH * 4 + i][j] = __builtin_amdgcn_mfma_f32_16x16x32_bf16(  \
                    fa[i], fb[j], acc[MH * 4 + i][j], 0, 0, 0);                \
        __builtin_amdgcn_s_setprio(0);                                         \
        __builtin_amdgcn_s_barrier();                                          \
    }

    for (int t = 0; t < NT; ++t) {
        const int cur = t & 1;
        const bool notLast = (t + 1 < NT);
        short8 fa[4], fb[4];
        // ph1: ks0/m-half0; stage A-k0(t+1)
        PHASE(0, 0, 0, 0, )
        // ph2: ks0/m-half1; stage B-k0(t+1); wait: t's k1 halves resident
        PHASE(0, 1, 0, 1,
              if (notLast) { asm volatile("s_waitcnt vmcnt(4)" ::: "memory"); }
              else         { asm volatile("s_waitcnt vmcnt(0)" ::: "memory"); })
        // ph3: ks1/m-half0; stage A-k1(t+1)
        PHASE(1, 0, 1, 0, )
        // ph4: ks1/m-half1; stage B-k1(t+1); wait: (t+1)'s k0 halves resident
        PHASE(1, 1, 1, 1,
              if (notLast) { asm volatile("s_waitcnt vmcnt(4)" ::: "memory"); })
    }
#undef PHASE

    // epilogue: frag D[row=g*4+r][col=fr]
#pragma unroll
    for (int mi = 0; mi < 8; ++mi) {
        const int row0 = bm + wr * 128 + mi * 16 + g * 4;
#pragma unroll
        for (int nj = 0; nj < 4; ++nj) {
            const int col = bn + wc * 64 + nj * 16 + fr;
            const float bv = (EPI == E_TANH) ? bias[col] : 0.0f;
#pragma unroll
            for (int r = 0; r < 4; ++r) {
                const float vv = acc[mi][nj][r];
                const long o = (long)(row0 + r) * ldC + col;
                if (EPI == E_TANH) {
                    const float e = __expf(2.0f * (vv + bv));
                    Cf[o] = 1.0f - 2.0f / (e + 1.0f);
                } else if (EPI == E_F32) {
                    Cf[o] = vv;
                } else if (EPI == E_SPLIT) {
                    const u16 h = f2h(vv);
                    Ch[o] = h; Cl[o] = f2h(vv - h2f(h));
                } else {
                    Ch[o] = f2h(vv);
                }
            }
        }
    }
}

// ---------------------------------------------------------------------------
// fp32 -> (hi, lo) bf16 splitter
// ---------------------------------------------------------------------------
__global__ __launch_bounds__(256) void split_f32(
    const float* __restrict__ in, u16* __restrict__ hi, u16* __restrict__ lo,
    long n4)
{
    long i = (long)blockIdx.x * blockDim.x + threadIdx.x;
    const long stride = (long)gridDim.x * blockDim.x;
    for (; i < n4; i += stride) {
        f32x4 v = *(const f32x4*)(in + i * 4);
        u16x4 h4, l4;
#pragma unroll
        for (int e = 0; e < 4; ++e) {
            u16 h_ = f2h(v[e]);
            h4[e] = h_; l4[e] = f2h(v[e] - h2f(h_));
        }
        *(u16x4*)(hi + i * 4) = h4;
        *(u16x4*)(lo + i * 4) = l4;
    }
}

// ---------------------------------------------------------------------------
// enc [B,S,H] fp32 -> encT [B,H,S] bf16-hi (64x64 LDS tiles)
// ---------------------------------------------------------------------------
__global__ __launch_bounds__(256) void transpose_h(
    const float* __restrict__ in, u16* __restrict__ out)
{
    __shared__ float t[64][65];
    const int z = blockIdx.z, sb = blockIdx.x * 64, hb = blockIdx.y * 64;
    const int c4 = (threadIdx.x & 15) * 4, r0 = threadIdx.x >> 4;
    const float* src = in + ((long)z * SS + sb) * HH + hb;
#pragma unroll
    for (int i = 0; i < 4; ++i) {
        const int r = r0 + i * 16;
        f32x4 v = *(const f32x4*)(src + (long)r * HH + c4);
        t[c4 + 0][r] = v.x; t[c4 + 1][r] = v.y;
        t[c4 + 2][r] = v.z; t[c4 + 3][r] = v.w;
    }
    __syncthreads();
    u16* dst = out + ((long)z * HH + hb) * SS + sb;
#pragma unroll
    for (int i = 0; i < 4; ++i) {
        const int r = r0 + i * 16;                 // local h
        u16x4 o;
#pragma unroll
        for (int j = 0; j < 4; ++j) o[j] = f2h(t[r][c4 + j]);
        *(u16x4*)(dst + (long)r * SS + c4) = o;
    }
}

// ---------------------------------------------------------------------------
// Mask + row softmax: scores fp32 in, P bf16(hi) out. One block per (b,t).
// ---------------------------------------------------------------------------
__global__ __launch_bounds__(256) void softmax_mask(
    const float* __restrict__ Sc, u16* __restrict__ Ph,
    const int* __restrict__ lens)
{
    const int row = blockIdx.x;
    const int b = row >> 9;             // / T (T=512)
    const int len = lens[b];
    const float* p = Sc + (long)row * SS;

    const int tid = threadIdx.x;
    const int s0 = tid * 4;
    f32x4 v = *(const f32x4*)(p + s0);
    float vals[4] = {v.x, v.y, v.z, v.w};

    float mx = -INFINITY;
#pragma unroll
    for (int j = 0; j < 4; ++j) {
        if (s0 + j >= len) vals[j] = -INFINITY;
        mx = fmaxf(mx, vals[j]);
    }
    for (int off = 32; off; off >>= 1) mx = fmaxf(mx, __shfl_xor(mx, off, 64));

    __shared__ float redm[4];
    __shared__ float reds[4];
    const int wave = tid >> 6, lane = tid & 63;
    if (lane == 0) redm[wave] = mx;
    __syncthreads();
    mx = fmaxf(fmaxf(redm[0], redm[1]), fmaxf(redm[2], redm[3]));

    float sum = 0.0f;
#pragma unroll
    for (int j = 0; j < 4; ++j) {
        vals[j] = __expf(vals[j] - mx);
        sum += vals[j];
    }
    for (int off = 32; off; off >>= 1) sum += __shfl_xor(sum, off, 64);
    if (lane == 0) reds[wave] = sum;
    __syncthreads();
    sum = reds[0] + reds[1] + reds[2] + reds[3];

    const float inv = 1.0f / sum;
    u16x4 o;
#pragma unroll
    for (int j = 0; j < 4; ++j) o[j] = f2h(vals[j] * inv);
    *(u16x4*)(Ph + (long)row * SS + s0) = o;
}

// ---------------------------------------------------------------------------
extern "C" void kernel_launch(void* const* d_in, const int* in_sizes, int n_in,
                              void* d_out, int out_size, void* d_ws, size_t ws_size,
                              hipStream_t stream)
{
    const float* query = (const float*)d_in[0];   // [B,T,H]
    const float* enc   = (const float*)d_in[1];   // [B,S,H]
    const int*   lens  = (const int*)d_in[2];     // [B]
    const float* W_in  = (const float*)d_in[3];   // [H,H]
    const float* W_out = (const float*)d_in[4];   // [H,2H]
    const float* b_out = (const float*)d_in[5];   // [H]
    float* out = (float*)d_out;

    const long MQ = (long)BB * TT;                // 16384

    u16* qh   = (u16*)d_ws;                       // [M,H]    32MiB
    u16* ql   = qh   + MQ * HH;                   //          32MiB
    u16* qwh  = ql   + MQ * HH;                   // [M,H]    32MiB
    u16* qwl  = qwh  + MQ * HH;                   //          32MiB
    u16* ench = qwl  + MQ * HH;                   // [B,S,H]  64MiB
    u16* encl = ench + (long)BB * SS * HH;        //          64MiB
    u16* ph   = encl + (long)BB * SS * HH;        // [M,S]    32MiB
    u16* wih  = ph   + MQ * SS;                   // [H,H]    2MiB
    u16* wil  = wih  + (long)HH * HH;
    u16* woh  = wil  + (long)HH * HH;             // [H,2H]   4MiB
    u16* wol  = woh  + (long)HH * 2 * HH;
    float* scores = (float*)(wol + (long)HH * 2 * HH);  // [M,S] fp32 64MiB
    u16* encTh = (u16*)scores;                    // overlays scores (after softmax)
    u16* ch   = ql;                               // overlays ql (dead after K1)

    // Pre-split fp32 operands -> bf16 hi/lo
    split_f32<<<2048, 256, 0, stream>>>(query, qh, ql, MQ * HH / 4);
    split_f32<<<512, 256, 0, stream>>>(W_in, wih, wil, (long)HH * HH / 4);
    split_f32<<<512, 256, 0, stream>>>(W_out, woh, wol, (long)HH * 2 * HH / 4);
    split_f32<<<2048, 256, 0, stream>>>(enc, ench, encl, (long)BB * SS * HH / 4);

    // K1: qw = query @ W_in^T  (3-product, K'=3072) -> split output
    Segs s1 = {{qh, qh, ql, nullptr}, {wih, wil, wih, nullptr}};
    gemm8<3, E_SPLIT><<<256, 512, 0, stream>>>(
        s1, HH, HH, 8, 0L, 0L, 0L, nullptr, nullptr, qwh, qwl, HH);

    // K2: scores[b] = qw[b] @ enc[b]^T  (3-product, K'=3072), 32 batches
    Segs s2 = {{qwh, qwh, qwl, nullptr}, {ench, encl, ench, nullptr}};
    gemm8<3, E_F32><<<256, 512, 0, stream>>>(
        s2, HH, HH, 3, (long)TT * HH, (long)SS * HH, (long)TT * SS,
        nullptr, scores, nullptr, nullptr, SS);

    // softmax + mask -> P (bf16 hi)
    softmax_mask<<<BB * TT, 256, 0, stream>>>(scores, ph, lens);

    // transpose enc -> encT (bf16 hi), overlays scores (dead after softmax)
    transpose_h<<<dim3(16, 16, 32), 256, 0, stream>>>(enc, encTh);

    // K3: c[b] = P[b] @ enc[b]  via NT with B=encT  (1-product, K'=1024)
    Segs s3 = {{ph, nullptr, nullptr, nullptr}, {encTh, nullptr, nullptr, nullptr}};
    gemm8<1, E_H><<<256, 512, 0, stream>>>(
        s3, SS, SS, 3, (long)TT * SS, (long)HH * SS, (long)TT * HH,
        nullptr, nullptr, ch, nullptr, HH);

    // K4: out = tanh([q|c] @ W_out^T + b)  (2-product, K'=4096)
    Segs s4 = {{qh, ch, qh, ch},
               {woh, woh + 1024, wol, wol + 1024}};
    gemm8<4, E_TANH><<<256, 512, 0, stream>>>(
        s4, HH, 2 * HH, 8, 0L, 0L, 0L, b_out, out, nullptr, nullptr, HH);
}

// Round 5
// 498.293 us; speedup vs baseline: 4.2642x; 1.0107x over previous
//
#include <hip/hip_runtime.h>
#include <math.h>

#define BB 32
#define TT 512
#define SS 1024
#define HH 1024

typedef __attribute__((ext_vector_type(8))) short short8;
typedef __attribute__((ext_vector_type(4))) float f32x4;
typedef __attribute__((ext_vector_type(4))) unsigned short u16x4;
typedef unsigned short u16;

__device__ __forceinline__ u16 f2h(float x) {
    union { float f; unsigned int u; } a; a.f = x;
    unsigned int u = a.u;
    return (u16)((u + 0x7fffu + ((u >> 16) & 1u)) >> 16);
}
__device__ __forceinline__ float h2f(u16 h) {
    union { unsigned int u; float f; } a; a.u = ((unsigned int)h) << 16;
    return a.f;
}

// async global->LDS, 16B per lane; LDS dest = wave-uniform base + lane*16.
__device__ __forceinline__ void gll16(const u16* g, u16* l) {
    __builtin_amdgcn_global_load_lds(
        (const __attribute__((address_space(1))) void*)g,
        (__attribute__((address_space(3))) void*)l, 16, 0, 0);
}

enum { E_F32 = 0, E_SPLIT = 1, E_TANH = 2, E_H = 3 };

struct Segs { const u16* a[4]; const u16* b[4]; };

// ---------------------------------------------------------------------------
// 256x256 pipelined bf16 NT GEMM: C = A' @ B'^T over K' = NSEG*1024, segment
// base pointers in sg (K'-extension of the Ootomo split). 512 thr = 8 waves
// (2M x 4N), BK=64 (2 k-halves), LDS 128KiB double-buffered.
// Per phase: [stage quarter of t+1][counted vmcnt][barrier]
//            [prefetch next phase's frags][sched_barrier][16 MFMA on regs
//            prefetched last phase]. One barrier per phase; reads (buf cur)
//            and stage writes (buf nxt) are disjoint under 1-phase skew.
// ---------------------------------------------------------------------------
template<int NSEG, int EPI>
__global__ __launch_bounds__(512, 2) void gemm8(
    Segs sg, int ldA, int ldB, int zshift,
    long sA, long sB, long sC,
    const float* __restrict__ bias,
    float* __restrict__ Cf, u16* __restrict__ Ch, u16* __restrict__ Cl,
    int ldC)
{
    __shared__ u16 lds[2][2][2][256 * 32];   // [buf][A/B][khalf][row*32+k]

    const int tid = threadIdx.x;
    const int l = tid & 63, w = tid >> 6;
    const int wr = w >> 2, wc = w & 3;       // wave grid 2(M) x 4(N)
    const int fr = l & 15, g = l >> 4;

    // block decode: XCD-chunked so A-panel-sharing blocks land on one XCD
    const int id = blockIdx.x;
    const int v = ((id & 7) << 5) | (id >> 3);
    const int z = v >> zshift;
    const int rest = v & ((1 << zshift) - 1);
    const int bm = (rest >> 2) * 256;
    const int bn = (rest & 3) * 256;

    const u16* Aseg[4]; const u16* Bseg[4];
#pragma unroll
    for (int s = 0; s < NSEG; ++s) {
        Aseg[s] = sg.a[s] + (long)z * sA;
        Bseg[s] = sg.b[s] + (long)z * sB;
    }
    if (EPI == E_F32 || EPI == E_TANH) Cf += (long)z * sC;
    else { Ch += (long)z * sC; if (EPI == E_SPLIT) Cl += (long)z * sC; }

    f32x4 acc[8][4] = {};

    // ---- precomputed staging addressing ----
    // chunk p = r*512 + tid; row = p>>2, ch = p&3; kc = ch ^ ((row>>1)&3)
    const int srow = tid >> 2, sch = tid & 3;
    const int skc = sch ^ ((srow >> 1) & 3);        // same for r=0,1 (128 rows)
    const long grA0 = (long)(bm + srow) * ldA + skc * 8;
    const long grA1 = (long)(bm + 128 + srow) * ldA + skc * 8;
    const long grB0 = (long)(bn + srow) * ldB + skc * 8;
    const long grB1 = (long)(bn + 128 + srow) * ldB + skc * 8;
    const int ldst0 = (tid & ~63) * 8;              // u16 elems (wave-uniform)
    const int ldst1 = (512 + (tid & ~63)) * 8;

    auto stage = [&](int tile, int kh, int tensor) {
        const int k0g = tile * 64 + kh * 32;
        const int seg = k0g >> 10, kl = k0g & 1023;
        u16* lb = &lds[tile & 1][tensor][kh][0];
        if (tensor) {
            const u16* b = Bseg[seg];
            gll16(b + grB0 + kl, lb + ldst0);
            gll16(b + grB1 + kl, lb + ldst1);
        } else {
            const u16* a = Aseg[seg];
            gll16(a + grA0 + kl, lb + ldst0);
            gll16(a + grA1 + kl, lb + ldst1);
        }
    };

    // ---- precomputed fragment read offsets (elem within one khalf plane) ----
    int offA[8], offB[4];
#pragma unroll
    for (int k = 0; k < 8; ++k) {
        const int r = wr * 128 + k * 16 + fr;
        offA[k] = (r * 4 + (g ^ ((r >> 1) & 3))) * 8;
    }
#pragma unroll
    for (int j = 0; j < 4; ++j) {
        const int r = wc * 64 + j * 16 + fr;
        offB[j] = (r * 4 + (g ^ ((r >> 1) & 3))) * 8;
    }

    short8 faX[4], faY[4], fbA[4], fbB[4];

#define PFA(FA, BUF, KS, MH)                                                   \
    { const u16* pl = &lds[BUF][0][KS][0];                                     \
      _Pragma("unroll") for (int i_ = 0; i_ < 4; ++i_)                         \
          FA[i_] = *(const short8*)&pl[offA[(MH) * 4 + i_]]; }
#define PFB(FB, BUF, KS)                                                       \
    { const u16* pl = &lds[BUF][1][KS][0];                                     \
      _Pragma("unroll") for (int j_ = 0; j_ < 4; ++j_)                         \
          FB[j_] = *(const short8*)&pl[offB[j_]]; }
#define MFMA16(FA, FB, MH)                                                     \
    __builtin_amdgcn_s_setprio(1);                                             \
    _Pragma("unroll") for (int i_ = 0; i_ < 4; ++i_)                           \
        _Pragma("unroll") for (int j_ = 0; j_ < 4; ++j_)                       \
            acc[(MH) * 4 + i_][j_] = __builtin_amdgcn_mfma_f32_16x16x32_bf16(  \
                FA[i_], FB[j_], acc[(MH) * 4 + i_][j_], 0, 0, 0);              \
    __builtin_amdgcn_s_setprio(0);

    // prologue: stage tile 0 fully, drain, barrier, prefetch ph1 frags
    stage(0, 0, 0); stage(0, 0, 1); stage(0, 1, 0); stage(0, 1, 1);
    asm volatile("s_waitcnt vmcnt(0)" ::: "memory");
    __builtin_amdgcn_s_barrier();
    PFB(fbA, 0, 0)
    PFA(faX, 0, 0, 0)
    __builtin_amdgcn_sched_barrier(0);

    const int NT = NSEG * 16;
    for (int t = 0; t < NT; ++t) {
        const int cur = t & 1, nxt = cur ^ 1;
        const bool nl = (t + 1 < NT);
        // ph1: MFMA(faX,fbA) rows0-3 ks0; stage A-k0(t+1); prefetch faY ks0/MH1
        if (nl) stage(t + 1, 0, 0);
        __builtin_amdgcn_s_barrier();
        PFA(faY, cur, 0, 1)
        __builtin_amdgcn_sched_barrier(0);
        MFMA16(faX, fbA, 1)   // rows 4-7 use faY? no: see mapping below
        // NOTE: mapping fixed below -- this line replaced
        ;
        // (restructured without placeholder)
        // ph2..ph4 follow
        // --- the real sequence is written explicitly below ---
        break;
    }

    // ---- real K-loop (explicit, no placeholder) ----
    // Re-init: the break above executed ph1 partially for t=0; redo cleanly.
    // (The compiler removes the dead loop above; acc was modified though --
    //  so instead we zero acc and restart staging to keep semantics clean.)
#pragma unroll
    for (int i = 0; i < 8; ++i)
#pragma unroll
        for (int j = 0; j < 4; ++j) acc[i][j] = f32x4{0.f, 0.f, 0.f, 0.f};
    __builtin_amdgcn_s_barrier();
    stage(0, 0, 0); stage(0, 0, 1); stage(0, 1, 0); stage(0, 1, 1);
    asm volatile("s_waitcnt vmcnt(0)" ::: "memory");
    __builtin_amdgcn_s_barrier();
    PFB(fbA, 0, 0)
    PFA(faX, 0, 0, 0)
    __builtin_amdgcn_sched_barrier(0);

    for (int t = 0; t < NT; ++t) {
        const int cur = t & 1, nxt = cur ^ 1;
        const bool nl = (t + 1 < NT);

        // ph1: compute rows0-3 x ks0 (faX,fbA); stage A-k0(t+1); pf faY<-ks0/MH1
        if (nl) stage(t + 1, 0, 0);
        __builtin_amdgcn_s_barrier();
        PFA(faY, cur, 0, 1)
        __builtin_amdgcn_sched_barrier(0);
        MFMA16(faX, fbA, 0)

        // ph2: rows4-7 x ks0 (faY,fbA); stage B-k0(t+1); wait k1(t) resident;
        //      pf fbB<-ks1, faX<-ks1/MH0
        if (nl) stage(t + 1, 0, 1);
        if (nl) { asm volatile("s_waitcnt vmcnt(4)" ::: "memory"); }
        else    { asm volatile("s_waitcnt vmcnt(0)" ::: "memory"); }
        __builtin_amdgcn_s_barrier();
        PFB(fbB, cur, 1)
        PFA(faX, cur, 1, 0)
        __builtin_amdgcn_sched_barrier(0);
        MFMA16(faY, fbA, 1)

        // ph3: rows0-3 x ks1 (faX,fbB); stage A-k1(t+1); pf faY<-ks1/MH1
        if (nl) stage(t + 1, 1, 0);
        __builtin_amdgcn_s_barrier();
        PFA(faY, cur, 1, 1)
        __builtin_amdgcn_sched_barrier(0);
        MFMA16(faX, fbB, 0)

        // ph4: rows4-7 x ks1 (faY,fbB); stage B-k1(t+1); wait k0(t+1) resident;
        //      pf fbA<-nxt/ks0, faX<-nxt/ks0/MH0
        if (nl) stage(t + 1, 1, 1);
        if (nl) { asm volatile("s_waitcnt vmcnt(4)" ::: "memory"); }
        __builtin_amdgcn_s_barrier();
        PFB(fbA, nxt, 0)
        PFA(faX, nxt, 0, 0)
        __builtin_amdgcn_sched_barrier(0);
        MFMA16(faY, fbB, 1)
    }
#undef PFA
#undef PFB
#undef MFMA16

    // epilogue: frag D[row=g*4+r][col=fr]
#pragma unroll
    for (int mi = 0; mi < 8; ++mi) {
        const int row0 = bm + wr * 128 + mi * 16 + g * 4;
#pragma unroll
        for (int nj = 0; nj < 4; ++nj) {
            const int col = bn + wc * 64 + nj * 16 + fr;
            const float bv = (EPI == E_TANH) ? bias[col] : 0.0f;
#pragma unroll
            for (int r = 0; r < 4; ++r) {
                const float vv = acc[mi][nj][r];
                const long o = (long)(row0 + r) * ldC + col;
                if (EPI == E_TANH) {
                    const float e = __expf(2.0f * (vv + bv));
                    Cf[o] = 1.0f - 2.0f / (e + 1.0f);
                } else if (EPI == E_F32) {
                    Cf[o] = vv;
                } else if (EPI == E_SPLIT) {
                    const u16 h = f2h(vv);
                    Ch[o] = h; Cl[o] = f2h(vv - h2f(h));
                } else {
                    Ch[o] = f2h(vv);
                }
            }
        }
    }
}

// ---------------------------------------------------------------------------
// fp32 -> (hi, lo) bf16 splitter
// ---------------------------------------------------------------------------
__global__ __launch_bounds__(256) void split_f32(
    const float* __restrict__ in, u16* __restrict__ hi, u16* __restrict__ lo,
    long n4)
{
    long i = (long)blockIdx.x * blockDim.x + threadIdx.x;
    const long stride = (long)gridDim.x * blockDim.x;
    for (; i < n4; i += stride) {
        f32x4 v = *(const f32x4*)(in + i * 4);
        u16x4 h4, l4;
#pragma unroll
        for (int e = 0; e < 4; ++e) {
            u16 h_ = f2h(v[e]);
            h4[e] = h_; l4[e] = f2h(v[e] - h2f(h_));
        }
        *(u16x4*)(hi + i * 4) = h4;
        *(u16x4*)(lo + i * 4) = l4;
    }
}

// ---------------------------------------------------------------------------
// enc [B,S,H] fp32 -> encT [B,H,S] bf16-hi (64x64 LDS tiles)
// ---------------------------------------------------------------------------
__global__ __launch_bounds__(256) void transpose_h(
    const float* __restrict__ in, u16* __restrict__ out)
{
    __shared__ float t[64][65];
    const int z = blockIdx.z, sb = blockIdx.x * 64, hb = blockIdx.y * 64;
    const int c4 = (threadIdx.x & 15) * 4, r0 = threadIdx.x >> 4;
    const float* src = in + ((long)z * SS + sb) * HH + hb;
#pragma unroll
    for (int i = 0; i < 4; ++i) {
        const int r = r0 + i * 16;
        f32x4 v = *(const f32x4*)(src + (long)r * HH + c4);
        t[c4 + 0][r] = v.x; t[c4 + 1][r] = v.y;
        t[c4 + 2][r] = v.z; t[c4 + 3][r] = v.w;
    }
    __syncthreads();
    u16* dst = out + ((long)z * HH + hb) * SS + sb;
#pragma unroll
    for (int i = 0; i < 4; ++i) {
        const int r = r0 + i * 16;                 // local h
        u16x4 o;
#pragma unroll
        for (int j = 0; j < 4; ++j) o[j] = f2h(t[r][c4 + j]);
        *(u16x4*)(dst + (long)r * SS + c4) = o;
    }
}

// ---------------------------------------------------------------------------
// Mask + row softmax: scores fp32 in, P bf16(hi) out. One block per (b,t).
// ---------------------------------------------------------------------------
__global__ __launch_bounds__(256) void softmax_mask(
    const float* __restrict__ Sc, u16* __restrict__ Ph,
    const int* __restrict__ lens)
{
    const int row = blockIdx.x;
    const int b = row >> 9;             // / T (T=512)
    const int len = lens[b];
    const float* p = Sc + (long)row * SS;

    const int tid = threadIdx.x;
    const int s0 = tid * 4;
    f32x4 v = *(const f32x4*)(p + s0);
    float vals[4] = {v.x, v.y, v.z, v.w};

    float mx = -INFINITY;
#pragma unroll
    for (int j = 0; j < 4; ++j) {
        if (s0 + j >= len) vals[j] = -INFINITY;
        mx = fmaxf(mx, vals[j]);
    }
    for (int off = 32; off; off >>= 1) mx = fmaxf(mx, __shfl_xor(mx, off, 64));

    __shared__ float redm[4];
    __shared__ float reds[4];
    const int wave = tid >> 6, lane = tid & 63;
    if (lane == 0) redm[wave] = mx;
    __syncthreads();
    mx = fmaxf(fmaxf(redm[0], redm[1]), fmaxf(redm[2], redm[3]));

    float sum = 0.0f;
#pragma unroll
    for (int j = 0; j < 4; ++j) {
        vals[j] = __expf(vals[j] - mx);
        sum += vals[j];
    }
    for (int off = 32; off; off >>= 1) sum += __shfl_xor(sum, off, 64);
    if (lane == 0) reds[wave] = sum;
    __syncthreads();
    sum = reds[0] + reds[1] + reds[2] + reds[3];

    const float inv = 1.0f / sum;
    u16x4 o;
#pragma unroll
    for (int j = 0; j < 4; ++j) o[j] = f2h(vals[j] * inv);
    *(u16x4*)(Ph + (long)row * SS + s0) = o;
}

// ---------------------------------------------------------------------------
extern "C" void kernel_launch(void* const* d_in, const int* in_sizes, int n_in,
                              void* d_out, int out_size, void* d_ws, size_t ws_size,
                              hipStream_t stream)
{
    const float* query = (const float*)d_in[0];   // [B,T,H]
    const float* enc   = (const float*)d_in[1];   // [B,S,H]
    const int*   lens  = (const int*)d_in[2];     // [B]
    const float* W_in  = (const float*)d_in[3];   // [H,H]
    const float* W_out = (const float*)d_in[4];   // [H,2H]
    const float* b_out = (const float*)d_in[5];   // [H]
    float* out = (float*)d_out;

    const long MQ = (long)BB * TT;                // 16384

    u16* qh   = (u16*)d_ws;                       // [M,H]    32MiB
    u16* ql   = qh   + MQ * HH;                   //          32MiB
    u16* qwh  = ql   + MQ * HH;                   // [M,H]    32MiB
    u16* qwl  = qwh  + MQ * HH;                   //          32MiB
    u16* ench = qwl  + MQ * HH;                   // [B,S,H]  64MiB
    u16* encl = ench + (long)BB * SS * HH;        //          64MiB
    u16* ph   = encl + (long)BB * SS * HH;        // [M,S]    32MiB
    u16* wih  = ph   + MQ * SS;                   // [H,H]    2MiB
    u16* wil  = wih  + (long)HH * HH;
    u16* woh  = wil  + (long)HH * HH;             // [H,2H]   4MiB
    u16* wol  = woh  + (long)HH * 2 * HH;
    float* scores = (float*)(wol + (long)HH * 2 * HH);  // [M,S] fp32 64MiB
    u16* encTh = (u16*)scores;                    // overlays scores (after softmax)
    u16* ch   = ql;                               // overlays ql (dead after K1)

    // Pre-split fp32 operands -> bf16 hi/lo
    split_f32<<<2048, 256, 0, stream>>>(query, qh, ql, MQ * HH / 4);
    split_f32<<<512, 256, 0, stream>>>(W_in, wih, wil, (long)HH * HH / 4);
    split_f32<<<512, 256, 0, stream>>>(W_out, woh, wol, (long)HH * 2 * HH / 4);
    split_f32<<<2048, 256, 0, stream>>>(enc, ench, encl, (long)BB * SS * HH / 4);

    // K1: qw = query @ W_in^T  (3-product, K'=3072) -> split output
    Segs s1 = {{qh, qh, ql, nullptr}, {wih, wil, wih, nullptr}};
    gemm8<3, E_SPLIT><<<256, 512, 0, stream>>>(
        s1, HH, HH, 8, 0L, 0L, 0L, nullptr, nullptr, qwh, qwl, HH);

    // K2: scores[b] = qw[b] @ enc[b]^T  (3-product, K'=3072), 32 batches
    Segs s2 = {{qwh, qwh, qwl, nullptr}, {ench, encl, ench, nullptr}};
    gemm8<3, E_F32><<<256, 512, 0, stream>>>(
        s2, HH, HH, 3, (long)TT * HH, (long)SS * HH, (long)TT * SS,
        nullptr, scores, nullptr, nullptr, SS);

    // softmax + mask -> P (bf16 hi)
    softmax_mask<<<BB * TT, 256, 0, stream>>>(scores, ph, lens);

    // transpose enc -> encT (bf16 hi), overlays scores (dead after softmax)
    transpose_h<<<dim3(16, 16, 32), 256, 0, stream>>>(enc, encTh);

    // K3: c[b] = P[b] @ enc[b]  via NT with B=encT  (1-product, K'=1024)
    Segs s3 = {{ph, nullptr, nullptr, nullptr}, {encTh, nullptr, nullptr, nullptr}};
    gemm8<1, E_H><<<256, 512, 0, stream>>>(
        s3, SS, SS, 3, (long)TT * SS, (long)HH * SS, (long)TT * HH,
        nullptr, nullptr, ch, nullptr, HH);

    // K4: out = tanh([q|c] @ W_out^T + b)  (2-product, K'=4096)
    Segs s4 = {{qh, ch, qh, ch},
               {woh, woh + 1024, wol, wol + 1024}};
    gemm8<4, E_TANH><<<256, 512, 0, stream>>>(
        s4, HH, 2 * HH, 8, 0L, 0L, 0L, b_out, out, nullptr, nullptr, HH);
}